// Round 1
// baseline (2071.369 us; speedup 1.0000x reference)
//
#include <hip/hip_runtime.h>
#include <stdint.h>

// Problem constants (fixed by the reference)
#define Bn 32
#define Cn 64
#define Vn 1024
#define Tn 24
#define Gn 192   // 3*C
#define O4 256   // 4*C

typedef __attribute__((ext_vector_type(8))) short bh8;   // 8 x bf16 (MFMA A/B frag)
typedef __attribute__((ext_vector_type(4))) short bh4;   // 4 x bf16 packed store
typedef __attribute__((ext_vector_type(4))) float f32x4; // MFMA C/D frag

__device__ __forceinline__ float bf2f(unsigned short u){
  union { unsigned int i; float f; } x; x.i = ((unsigned int)u) << 16; return x.f;
}
__device__ __forceinline__ unsigned short f2bf(float f){
  union { float f; unsigned int i; } x; x.f = f;
  unsigned int u = x.i;
  return (unsigned short)((u + 0x7fffu + ((u >> 16) & 1u)) >> 16); // RNE
}
__device__ __forceinline__ float sigm(float x){ return 1.f/(1.f+__expf(-x)); }
__device__ __forceinline__ float tanhfast(float x){ return 1.f - 2.f/(__expf(2.f*x)+1.f); }
__device__ __forceinline__ f32x4 fzero(){ f32x4 z = {0.f,0.f,0.f,0.f}; return z; }

// MFMA 16x16x32 frag loader (TN convention: both operands row-major with k contiguous).
// lane l holds X[idx = r0 + mf*16 + (l&15)][k = k0 + (l>>4)*8 + j], j=0..7  -> one b128 load.
__device__ __forceinline__ bh8 ld_frag(const unsigned short* base, int stride, int r0, int mf,
                                       int k0, int lane){
  int r  = r0 + mf*16 + (lane & 15);
  int kk = k0 + ((lane >> 4) << 3);
  return *(const bh8*)(base + (size_t)r * stride + kk);
}

// ---------------------------------------------------------------------------
// Prep: permute W_gout rows to o' = c*4 + gate (so one lane's f32x4 acc = i,f,g,o
// of a single channel), quantize to bf16; permute bias.
__global__ void k_prep_w(const float* __restrict__ Wg, const float* __restrict__ bg,
                         unsigned short* __restrict__ Wperm, float* __restrict__ bperm){
  int op = threadIdx.x;              // 0..255 = o'
  int gate = op & 3, c = op >> 2;
  int oo = gate * 64 + c;            // original row in W_gout
  for (int g = 0; g < Gn; ++g)
    Wperm[op * Gn + g] = f2bf(Wg[(size_t)oo * Gn + g]);
  bperm[op] = bg[oo];
}

// Quantize + transpose a 1024x1024 fp32 matrix: dst (optional) = bf16(src), dstT = bf16(src^T)
__global__ void k_transq(const float* __restrict__ src, unsigned short* dst,
                         unsigned short* __restrict__ dstT){
  __shared__ float tile[64][65];
  int j0 = blockIdx.x * 64, i0 = blockIdx.y * 64;
  for (int e = threadIdx.x; e < 4096; e += 256){
    int r = e >> 6, col = e & 63;
    float v = src[(size_t)(i0 + r) * Vn + j0 + col];
    if (dst) dst[(size_t)(i0 + r) * Vn + j0 + col] = f2bf(v);
    tile[r][col] = v;
  }
  __syncthreads();
  for (int e = threadIdx.x; e < 4096; e += 256){
    int r = e >> 6, col = e & 63;
    dstT[(size_t)(j0 + r) * Vn + i0 + col] = f2bf(tile[col][r]);
  }
}

// A2 = A @ A  (bf16 MFMA, fp32 out). D[m][n] = sum_k Ab[m][k] * ATb[n][k].
// 4 waves split K into quarters; LDS reduce. 256 blocks x 4 waves = 4 waves/CU.
__global__ __launch_bounds__(256) void k_gemm_a2(const unsigned short* __restrict__ Ab,
                                                 const unsigned short* __restrict__ ATb,
                                                 float* __restrict__ A2){
  __shared__ f32x4 red[3][4][4][64];   // 48 KB
  int lane = threadIdx.x & 63;
  int wv   = threadIdx.x >> 6;         // 0..3: K-quarter
  int n0 = blockIdx.x * 64, m0 = blockIdx.y * 64;
  f32x4 acc[4][4];
  #pragma unroll
  for (int i=0;i<4;i++)
    #pragma unroll
    for (int j=0;j<4;j++) acc[i][j] = fzero();
  int kbeg = wv * 256;
  #pragma unroll 2
  for (int k = kbeg; k < kbeg + 256; k += 32){
    bh8 a[4], b[4];
    #pragma unroll
    for (int mf=0; mf<4; ++mf) a[mf] = ld_frag(Ab, Vn, m0, mf, k, lane);
    #pragma unroll
    for (int nf=0; nf<4; ++nf) b[nf] = ld_frag(ATb, Vn, n0, nf, k, lane);
    #pragma unroll
    for (int mf=0; mf<4; ++mf)
      #pragma unroll
      for (int nf=0; nf<4; ++nf)
        acc[mf][nf] = __builtin_amdgcn_mfma_f32_16x16x32_bf16(a[mf], b[nf], acc[mf][nf], 0,0,0);
  }
  if (wv){
    #pragma unroll
    for (int mf=0; mf<4; ++mf)
      #pragma unroll
      for (int nf=0; nf<4; ++nf) red[wv-1][mf][nf][lane] = acc[mf][nf];
  }
  __syncthreads();
  if (!wv){
    #pragma unroll
    for (int mf=0; mf<4; ++mf)
      #pragma unroll
      for (int nf=0; nf<4; ++nf)
        #pragma unroll
        for (int q=0;q<3;q++) acc[mf][nf] += red[q][mf][nf][lane];
    #pragma unroll
    for (int mf=0; mf<4; ++mf){
      int rb = m0 + mf*16 + ((lane>>4)<<2);
      #pragma unroll
      for (int nf=0; nf<4; ++nf){
        int cc = n0 + nf*16 + (lane&15);
        #pragma unroll
        for (int r=0;r<4;r++) A2[(size_t)(rb+r)*Vn + cc] = acc[mf][nf][r];
      }
    }
  }
}

// x (B,C,V,T) fp32 -> xTc[t][b][v][c] bf16 (c contiguous)
__global__ void k_transpose_x(const float* __restrict__ x, unsigned short* __restrict__ xT){
  int tid = threadIdx.x;
  int c = tid & 63, vl = tid >> 6;
  int b = blockIdx.y;
  int v = blockIdx.x * 4 + vl;
  const float* xp = x + ((size_t)(b * Cn + c) * Vn + v) * Tn;
  float vals[24];
  #pragma unroll
  for (int q = 0; q < 6; ++q){
    float4 f = *(const float4*)(xp + q*4);
    vals[q*4+0]=f.x; vals[q*4+1]=f.y; vals[q*4+2]=f.z; vals[q*4+3]=f.w;
  }
  #pragma unroll
  for (int t = 0; t < Tn; ++t)
    xT[((size_t)(t*Bn + b) * Vn + v) * Cn + c] = f2bf(vals[t]);
}

// comb = x_t + h. Writes both layouts: combc[b][v][c] (gates B-op) and combmk[b*C+c][v] (GEMM A-op)
// Only used for t=0 now (h0 = 0 plane); later steps fuse comb into k_gates' epilogue.
__global__ __launch_bounds__(256) void k_comb(const unsigned short* __restrict__ xTc,
    const unsigned short* __restrict__ ys,
    unsigned short* __restrict__ combc, unsigned short* __restrict__ combmk, int t){
  __shared__ float tile[64][65];
  int b = blockIdx.y, v0 = blockIdx.x * 64;
  const unsigned short* xp = xTc + ((size_t)t*Bn + b) * Vn * Cn;
  const unsigned short* hp = ys  + ((size_t)t*Bn + b) * Vn * Cn;   // plane t = h_{t-1} (plane0 = 0)
  for (int e = threadIdx.x; e < 4096; e += 256){
    int vl = e >> 6, c = e & 63;
    size_t o = (size_t)(v0 + vl) * Cn + c;
    float s = bf2f(xp[o]) + bf2f(hp[o]);
    combc[(size_t)b*Vn*Cn + o] = f2bf(s);
    tile[vl][c] = s;
  }
  __syncthreads();
  for (int e = threadIdx.x; e < 4096; e += 256){
    int c = e >> 6, vl = e & 63;
    combmk[((size_t)b*Cn + c)*Vn + v0 + vl] = f2bf(tile[vl][c]);
  }
}

// Dual GEMM: x1 = comb@A, x2 = comb@A2.  M=2048 (b*C+c), N=1024 (w), K=1024 (v).
// 4 waves per block: wave = (mat in {x1,x2}) x (K-half). LDS reduce across K-halves.
// 512 blocks x 4 waves = 2048 waves = 8 waves/CU (vs 2 before) -> latency hiding + all 4 MFMA pipes.
// Outputs written transposed per batch: x?c[b][w][c] bf16 (c contiguous, for gates B-op).
__global__ __launch_bounds__(256) void k_dual(const unsigned short* __restrict__ comb_mk,
    const unsigned short* __restrict__ ATb, const unsigned short* __restrict__ A2Tb,
    unsigned short* __restrict__ x1c, unsigned short* __restrict__ x2c){
  __shared__ f32x4 red[2][4][4][64];   // 32 KB
  int lane = threadIdx.x & 63;
  int wid  = threadIdx.x >> 6;         // 0..3
  int mat  = wid & 1;                  // 0: x1 (A), 1: x2 (A2)
  int kh   = wid >> 1;                 // K-half
  int n0 = blockIdx.x * 64, m0 = blockIdx.y * 64;
  const unsigned short* Bp = mat ? A2Tb : ATb;
  f32x4 acc[4][4];
  #pragma unroll
  for (int i=0;i<4;i++)
    #pragma unroll
    for (int j=0;j<4;j++) acc[i][j] = fzero();
  int kbeg = kh * 512;
  #pragma unroll 2
  for (int k = kbeg; k < kbeg + 512; k += 32){
    bh8 a[4], bb[4];
    #pragma unroll
    for (int mf=0; mf<4; ++mf) a[mf]  = ld_frag(comb_mk, Vn, m0, mf, k, lane);
    #pragma unroll
    for (int nf=0; nf<4; ++nf) bb[nf] = ld_frag(Bp, Vn, n0, nf, k, lane);
    #pragma unroll
    for (int mf=0; mf<4; ++mf)
      #pragma unroll
      for (int nf=0; nf<4; ++nf)
        acc[mf][nf] = __builtin_amdgcn_mfma_f32_16x16x32_bf16(a[mf], bb[nf], acc[mf][nf], 0,0,0);
  }
  if (kh){
    #pragma unroll
    for (int mf=0; mf<4; ++mf)
      #pragma unroll
      for (int nf=0; nf<4; ++nf) red[mat][mf][nf][lane] = acc[mf][nf];
  }
  __syncthreads();
  if (!kh){
    #pragma unroll
    for (int mf=0; mf<4; ++mf)
      #pragma unroll
      for (int nf=0; nf<4; ++nf) acc[mf][nf] += red[mat][mf][nf][lane];
    int b = blockIdx.y;   // BM=64=C so m-tile == batch
    unsigned short* dst = mat ? x2c : x1c;
    #pragma unroll
    for (int mf=0; mf<4; ++mf){
      int cb = mf*16 + ((lane>>4)<<2);   // first of 4 consecutive channels held by this lane
      #pragma unroll
      for (int nf=0; nf<4; ++nf){
        int col = n0 + nf*16 + (lane&15);
        bh4 p;
        #pragma unroll
        for (int r=0;r<4;r++) p[r] = (short)f2bf(acc[mf][nf][r]);
        *(bh4*)(dst + ((size_t)b*Vn + col)*Cn + cb) = p;
      }
    }
  }
}

// Gates GEMM (Wperm @ [comb;x1;x2]) + fused LSTM pointwise + fused comb_{t+1} = x_{t+1} + h_t.
// M=256 (o'=c*4+gate), N=64 v-tile, K=192. Each lane's acc f32x4 = (i,f,cell,o) of one (c,v).
// Each m-tile block owns 16 channels -> every (b,v,c) of comb written exactly once across grid.
// combc is double-buffered (read t&1, write (t+1)&1) since this kernel reads comb(t) while
// producing comb(t+1); combmk is only read by the NEXT k_dual launch (no intra-kernel race).
__global__ __launch_bounds__(64) void k_gates(const unsigned short* __restrict__ Wperm,
    const float* __restrict__ bperm,
    const unsigned short* __restrict__ combc_rd, const unsigned short* __restrict__ x1c,
    const unsigned short* __restrict__ x2c,
    float* __restrict__ cst, unsigned short* __restrict__ ys,
    const unsigned short* __restrict__ xTc,
    unsigned short* __restrict__ combc_wr, unsigned short* __restrict__ combmk, int t){
  int lane = threadIdx.x;
  int v0 = blockIdx.x * 64, m0 = blockIdx.y * 64, b = blockIdx.z;
  f32x4 acc[4][4];
  #pragma unroll
  for (int i=0;i<4;i++)
    #pragma unroll
    for (int j=0;j<4;j++) acc[i][j] = fzero();
  #pragma unroll
  for (int ki = 0; ki < 6; ++ki){
    int hop = ki >> 1, koff = (ki & 1) * 32;
    const unsigned short* hb = (hop == 0 ? combc_rd : hop == 1 ? x1c : x2c) + (size_t)b * Vn * Cn;
    bh8 a[4], bb[4];
    #pragma unroll
    for (int mf=0; mf<4; ++mf) a[mf]  = ld_frag(Wperm, Gn, m0, mf, hop*64 + koff, lane);
    #pragma unroll
    for (int nf=0; nf<4; ++nf) bb[nf] = ld_frag(hb, Cn, v0, nf, koff, lane);
    #pragma unroll
    for (int mf=0; mf<4; ++mf)
      #pragma unroll
      for (int nf=0; nf<4; ++nf)
        acc[mf][nf] = __builtin_amdgcn_mfma_f32_16x16x32_bf16(a[mf], bb[nf], acc[mf][nf], 0,0,0);
  }
  const bool wrc = (t + 1 < Tn);
  unsigned short* ysp = ys + ((size_t)(t+1)*Bn + b) * Vn * Cn;  // plane t+1 = h_t
  const unsigned short* xnext = xTc + ((size_t)(t+1)*Bn + b) * Vn * Cn; // unused when !wrc
  unsigned short* ccp = combc_wr + (size_t)b * Vn * Cn;
  unsigned short* cmp = combmk   + (size_t)b * Cn * Vn;
  #pragma unroll
  for (int mf = 0; mf < 4; ++mf){
    int oprow = m0 + mf*16 + ((lane>>4)<<2);
    int c = oprow >> 2;
    float4 b4 = *(const float4*)(bperm + oprow);
    #pragma unroll
    for (int nf = 0; nf < 4; ++nf){
      int v = v0 + nf*16 + (lane & 15);
      float gi = sigm(acc[mf][nf][0] + b4.x);
      float gf = sigm(acc[mf][nf][1] + b4.y);
      float gg =      acc[mf][nf][2] + b4.z;     // cell gate used raw (no tanh) per reference
      float go = sigm(acc[mf][nf][3] + b4.w);
      size_t ci = ((size_t)b*Cn + c)*Vn + v;
      float cy = gf * cst[ci] + gi * gg;
      cst[ci] = cy;
      unsigned short hb16 = f2bf(go * tanhfast(cy));
      ysp[(size_t)v*Cn + c] = hb16;
      if (wrc){
        // comb_{t+1} = bf16(x_{t+1}) + bf16(h_t), matching old k_comb numerics exactly
        float s = bf2f(hb16) + bf2f(xnext[(size_t)v*Cn + c]);
        unsigned short cb = f2bf(s);
        ccp[(size_t)v*Cn + c] = cb;
        cmp[(size_t)c*Vn + v] = cb;
      }
    }
  }
}

// Output projection + transpose: out[b][o][v][t] = sum_c Wout[o][c]*hy_t[b][c][v] + bout[o]
// Block: (t-chunk of 4, v-tile of 32, b). float4 stores along t (full 16B, no partial lines).
__global__ __launch_bounds__(256) void k_proj(const unsigned short* __restrict__ ys,
    const float* __restrict__ Wout, const float* __restrict__ bout, float* __restrict__ out){
  __shared__ float hyt[4][32][68];
  __shared__ float wt[64][68];
  int tc = blockIdx.x;          // 0..5
  int v0 = blockIdx.y * 32;
  int b  = blockIdx.z;
  int tid = threadIdx.x;
  for (int e = tid; e < 4096; e += 256){ int o = e>>6, c = e&63; wt[o][c] = Wout[(size_t)o*64 + c]; }
  for (int e = tid; e < 8192; e += 256){
    int tt = e >> 11; int rem = e & 2047; int vl = rem >> 6; int c = rem & 63;
    int plane = tc*4 + tt + 1;
    hyt[tt][vl][c] = bf2f(ys[((size_t)plane*Bn + b)*Vn*Cn + (size_t)(v0+vl)*Cn + c]);
  }
  __syncthreads();
  int og = tid >> 3, vg = tid & 7;   // 32 o-groups x 8 v-groups; 2 o's, 4 v's each
  float acc[2][4][4];
  #pragma unroll
  for (int i=0;i<2;i++)
    #pragma unroll
    for (int j=0;j<4;j++)
      #pragma unroll
      for (int k=0;k<4;k++) acc[i][j][k] = 0.f;
  for (int c = 0; c < 64; c += 4){
    float4 w4[2];
    #pragma unroll
    for (int oo=0;oo<2;oo++) w4[oo] = *(const float4*)&wt[og*2+oo][c];
    #pragma unroll
    for (int vv=0; vv<4; ++vv)
      #pragma unroll
      for (int tt=0; tt<4; ++tt){
        float4 h4 = *(const float4*)&hyt[tt][vg*4+vv][c];
        #pragma unroll
        for (int oo=0;oo<2;oo++)
          acc[oo][vv][tt] += w4[oo].x*h4.x + w4[oo].y*h4.y + w4[oo].z*h4.z + w4[oo].w*h4.w;
      }
  }
  #pragma unroll
  for (int oo=0;oo<2;oo++){
    int o = og*2 + oo;
    float bo = bout[o];
    #pragma unroll
    for (int vv=0; vv<4; ++vv){
      int v = v0 + vg*4 + vv;
      float4 r4;
      r4.x = acc[oo][vv][0] + bo; r4.y = acc[oo][vv][1] + bo;
      r4.z = acc[oo][vv][2] + bo; r4.w = acc[oo][vv][3] + bo;
      *(float4*)(out + ((size_t)(b*64 + o)*Vn + v)*Tn + tc*4) = r4;
    }
  }
}

// ---------------------------------------------------------------------------
extern "C" void kernel_launch(void* const* d_in, const int* in_sizes, int n_in,
                              void* d_out, int out_size, void* d_ws, size_t ws_size,
                              hipStream_t stream){
  const float* x   = (const float*)d_in[0];
  const float* A   = (const float*)d_in[1];
  const float* Wg  = (const float*)d_in[2];
  const float* bg  = (const float*)d_in[3];
  const float* Wo  = (const float*)d_in[4];
  const float* bo  = (const float*)d_in[5];
  float* out = (float*)d_out;

  char* ws = (char*)d_ws;
  size_t off = 0;
  auto alloc = [&](size_t bytes)->char*{
    char* p = ws + off; off = (off + bytes + 255) & ~(size_t)255; return p;
  };
  const size_t PLANE = (size_t)Bn*Vn*Cn;   // elements per (b,v,c) plane
  unsigned short* Abf    = (unsigned short*)alloc((size_t)Vn*Vn*2);
  unsigned short* ATbf   = (unsigned short*)alloc((size_t)Vn*Vn*2);
  unsigned short* A2T    = (unsigned short*)alloc((size_t)Vn*Vn*2);
  float*          A2f    = (float*)         alloc((size_t)Vn*Vn*4);
  unsigned short* Wperm  = (unsigned short*)alloc((size_t)O4*Gn*2);
  float*          bperm  = (float*)         alloc((size_t)O4*4);
  unsigned short* xTc    = (unsigned short*)alloc((size_t)Tn*PLANE*2);
  unsigned short* ys     = (unsigned short*)alloc((size_t)(Tn+1)*PLANE*2);
  unsigned short* combc  = (unsigned short*)alloc(2*PLANE*2);         // double-buffered
  unsigned short* combmk = (unsigned short*)alloc(PLANE*2);
  unsigned short* x1c    = (unsigned short*)alloc(PLANE*2);
  unsigned short* x2c    = (unsigned short*)alloc(PLANE*2);
  float*          cst    = (float*)         alloc(PLANE*4);
  (void)in_sizes; (void)n_in; (void)out_size; (void)ws_size;

  // zero-init recurrent state (h0 plane of ys, c0)
  hipMemsetAsync(ys,  0, PLANE*2, stream);
  hipMemsetAsync(cst, 0, PLANE*4, stream);

  k_prep_w<<<1, 256, 0, stream>>>(Wg, bg, Wperm, bperm);
  k_transq<<<dim3(16,16), 256, 0, stream>>>(A, Abf, ATbf);
  k_gemm_a2<<<dim3(16,16), 256, 0, stream>>>(Abf, ATbf, A2f);
  k_transq<<<dim3(16,16), 256, 0, stream>>>(A2f, (unsigned short*)nullptr, A2T);
  k_transpose_x<<<dim3(256,32), 256, 0, stream>>>(x, xTc);

  // t=0 comb from zeroed h0 plane (writes combc buffer 0 + combmk)
  k_comb<<<dim3(16,Bn), 256, 0, stream>>>(xTc, ys, combc, combmk, 0);

  for (int t = 0; t < Tn; ++t){
    k_dual <<<dim3(16,32),   256, 0, stream>>>(combmk, ATbf, A2T, x1c, x2c);
    k_gates<<<dim3(16,4,Bn),  64, 0, stream>>>(Wperm, bperm,
                combc + (size_t)(t & 1) * PLANE, x1c, x2c, cst, ys,
                xTc, combc + (size_t)((t + 1) & 1) * PLANE, combmk, t);
  }
  k_proj<<<dim3(6,32,Bn), 256, 0, stream>>>(ys, Wo, bo, out);
}

// Round 2
// 1616.360 us; speedup vs baseline: 1.2815x; 1.2815x over previous
//
#include <hip/hip_runtime.h>
#include <stdint.h>

// Problem constants (fixed by the reference)
#define Bn 32
#define Cn 64
#define Vn 1024
#define Tn 24
#define Gn 192   // 3*C
#define O4 256   // 4*C
#define NT 24576 // Vn*Tn (linear n-dim of the projection GEMM)

typedef __attribute__((ext_vector_type(8))) short bh8;   // 8 x bf16 (MFMA A/B frag)
typedef __attribute__((ext_vector_type(4))) short bh4;   // 4 x bf16 packed store
typedef __attribute__((ext_vector_type(4))) float f32x4; // MFMA C/D frag

__device__ __forceinline__ float bf2f(unsigned short u){
  union { unsigned int i; float f; } x; x.i = ((unsigned int)u) << 16; return x.f;
}
__device__ __forceinline__ unsigned short f2bf(float f){
  union { float f; unsigned int i; } x; x.f = f;
  unsigned int u = x.i;
  return (unsigned short)((u + 0x7fffu + ((u >> 16) & 1u)) >> 16); // RNE
}
__device__ __forceinline__ float sigm(float x){ return 1.f/(1.f+__expf(-x)); }
__device__ __forceinline__ float tanhfast(float x){ return 1.f - 2.f/(__expf(2.f*x)+1.f); }
__device__ __forceinline__ f32x4 fzero(){ f32x4 z = {0.f,0.f,0.f,0.f}; return z; }

// async global->LDS, 16B per lane; LDS dest is wave-uniform base + lane*16
__device__ __forceinline__ void gload_lds16(const void* g, void* l){
  __builtin_amdgcn_global_load_lds(
      (const __attribute__((address_space(1))) void*)g,
      (__attribute__((address_space(3))) void*)l, 16, 0, 0);
}

// MFMA 16x16x32 frag loader (TN convention: both operands row-major with k contiguous).
// lane l holds X[idx = r0 + mf*16 + (l&15)][k = k0 + (l>>4)*8 + j], j=0..7  -> one b128 load.
__device__ __forceinline__ bh8 ld_frag(const unsigned short* base, int stride, int r0, int mf,
                                       int k0, int lane){
  int r  = r0 + mf*16 + (lane & 15);
  int kk = k0 + ((lane >> 4) << 3);
  return *(const bh8*)(base + (size_t)r * stride + kk);
}

// ---------------------------------------------------------------------------
// Prep: permute W_gout rows to o' = c*4 + gate, quantize to bf16; permute bias.
__global__ void k_prep_w(const float* __restrict__ Wg, const float* __restrict__ bg,
                         unsigned short* __restrict__ Wperm, float* __restrict__ bperm){
  int op = threadIdx.x;              // 0..255 = o'
  int gate = op & 3, c = op >> 2;
  int oo = gate * 64 + c;            // original row in W_gout
  for (int g = 0; g < Gn; ++g)
    Wperm[op * Gn + g] = f2bf(Wg[(size_t)oo * Gn + g]);
  bperm[op] = bg[oo];
}

// Split W_out (64x64 fp32) into bf16 hi + lo so the projection MFMA keeps ~fp32 accuracy.
__global__ void k_prep_wo(const float* __restrict__ Wo, unsigned short* __restrict__ Whi,
                          unsigned short* __restrict__ Wlo){
  int e = blockIdx.x * 256 + threadIdx.x;   // 4096 total
  float w = Wo[e];
  unsigned short hi = f2bf(w);
  Whi[e] = hi;
  Wlo[e] = f2bf(w - bf2f(hi));
}

// Quantize + transpose a 1024x1024 fp32 matrix: dst (optional) = bf16(src), dstT = bf16(src^T)
__global__ void k_transq(const float* __restrict__ src, unsigned short* dst,
                         unsigned short* __restrict__ dstT){
  __shared__ float tile[64][65];
  int j0 = blockIdx.x * 64, i0 = blockIdx.y * 64;
  for (int e = threadIdx.x; e < 4096; e += 256){
    int r = e >> 6, col = e & 63;
    float v = src[(size_t)(i0 + r) * Vn + j0 + col];
    if (dst) dst[(size_t)(i0 + r) * Vn + j0 + col] = f2bf(v);
    tile[r][col] = v;
  }
  __syncthreads();
  for (int e = threadIdx.x; e < 4096; e += 256){
    int r = e >> 6, col = e & 63;
    dstT[(size_t)(j0 + r) * Vn + i0 + col] = f2bf(tile[col][r]);
  }
}

// A2 = A @ A  (bf16 MFMA, fp32 out). 4 waves split K into quarters; LDS reduce.
__global__ __launch_bounds__(256) void k_gemm_a2(const unsigned short* __restrict__ Ab,
                                                 const unsigned short* __restrict__ ATb,
                                                 float* __restrict__ A2){
  __shared__ f32x4 red[3][4][4][64];   // 48 KB
  int lane = threadIdx.x & 63;
  int wv   = threadIdx.x >> 6;         // 0..3: K-quarter
  int n0 = blockIdx.x * 64, m0 = blockIdx.y * 64;
  f32x4 acc[4][4];
  #pragma unroll
  for (int i=0;i<4;i++)
    #pragma unroll
    for (int j=0;j<4;j++) acc[i][j] = fzero();
  int kbeg = wv * 256;
  #pragma unroll 2
  for (int k = kbeg; k < kbeg + 256; k += 32){
    bh8 a[4], b[4];
    #pragma unroll
    for (int mf=0; mf<4; ++mf) a[mf] = ld_frag(Ab, Vn, m0, mf, k, lane);
    #pragma unroll
    for (int nf=0; nf<4; ++nf) b[nf] = ld_frag(ATb, Vn, n0, nf, k, lane);
    #pragma unroll
    for (int mf=0; mf<4; ++mf)
      #pragma unroll
      for (int nf=0; nf<4; ++nf)
        acc[mf][nf] = __builtin_amdgcn_mfma_f32_16x16x32_bf16(a[mf], b[nf], acc[mf][nf], 0,0,0);
  }
  if (wv){
    #pragma unroll
    for (int mf=0; mf<4; ++mf)
      #pragma unroll
      for (int nf=0; nf<4; ++nf) red[wv-1][mf][nf][lane] = acc[mf][nf];
  }
  __syncthreads();
  if (!wv){
    #pragma unroll
    for (int mf=0; mf<4; ++mf)
      #pragma unroll
      for (int nf=0; nf<4; ++nf)
        #pragma unroll
        for (int q=0;q<3;q++) acc[mf][nf] += red[q][mf][nf][lane];
    #pragma unroll
    for (int mf=0; mf<4; ++mf){
      int rb = m0 + mf*16 + ((lane>>4)<<2);
      #pragma unroll
      for (int nf=0; nf<4; ++nf){
        int cc = n0 + nf*16 + (lane&15);
        #pragma unroll
        for (int r=0;r<4;r++) A2[(size_t)(rb+r)*Vn + cc] = acc[mf][nf][r];
      }
    }
  }
}

// x (B,C,V,T) fp32 -> xTc[t][b][v][c] bf16 (c contiguous)
__global__ void k_transpose_x(const float* __restrict__ x, unsigned short* __restrict__ xT){
  int tid = threadIdx.x;
  int c = tid & 63, vl = tid >> 6;
  int b = blockIdx.y;
  int v = blockIdx.x * 4 + vl;
  const float* xp = x + ((size_t)(b * Cn + c) * Vn + v) * Tn;
  float vals[24];
  #pragma unroll
  for (int q = 0; q < 6; ++q){
    float4 f = *(const float4*)(xp + q*4);
    vals[q*4+0]=f.x; vals[q*4+1]=f.y; vals[q*4+2]=f.z; vals[q*4+3]=f.w;
  }
  #pragma unroll
  for (int t = 0; t < Tn; ++t)
    xT[((size_t)(t*Bn + b) * Vn + v) * Cn + c] = f2bf(vals[t]);
}

// t=0 comb: h0 == 0 so comb = x_0. Writes combc[b][v][c] and combmk[b*C+c][v].
__global__ __launch_bounds__(256) void k_comb0(const unsigned short* __restrict__ xTc,
    unsigned short* __restrict__ combc, unsigned short* __restrict__ combmk){
  __shared__ unsigned short tile[64][65];
  int b = blockIdx.y, v0 = blockIdx.x * 64;
  const unsigned short* xp = xTc + (size_t)b * Vn * Cn;   // plane t=0
  for (int e = threadIdx.x; e < 4096; e += 256){
    int vl = e >> 6, c = e & 63;
    size_t o = (size_t)(v0 + vl) * Cn + c;
    unsigned short s = xp[o];
    combc[(size_t)b*Vn*Cn + o] = s;
    tile[vl][c] = s;
  }
  __syncthreads();
  for (int e = threadIdx.x; e < 4096; e += 256){
    int c = e >> 6, vl = e & 63;
    combmk[((size_t)b*Cn + c)*Vn + v0 + vl] = tile[vl][c];
  }
}

// Dual GEMM as one fused GEMM: C[M=2048][N=2048] = comb_mk[2048][1024] @ B2T[2048][1024]^T-row
// (B2T rows 0..1023 = A^T, rows 1024..2047 = A2^T).
// Tile 128x128, BK=64 staged in LDS via global_load_lds(16B) with XOR swizzle (rule #21:
// pre-swizzled SOURCE + swizzled ds_read). 8 waves = 2x2 output quadrants x 2 K-halves;
// f32 LDS reduce across K-halves. 256 blocks, 512 threads.
__global__ __launch_bounds__(512) void k_dual2(const unsigned short* __restrict__ comb_mk,
    const unsigned short* __restrict__ B2T,
    unsigned short* __restrict__ x1c, unsigned short* __restrict__ x2c){
  __shared__ unsigned short As[8192];   // 128 rows x 64 k, 16 KB, swizzled
  __shared__ unsigned short Bs[8192];   // 16 KB
  __shared__ f32x4 red[4][16][64];      // 64 KB reduce buffer
  int tid = threadIdx.x;
  int lane = tid & 63, wid = tid >> 6;  // 8 waves
  int quad = wid & 3, kh = wid >> 2;    // quad: output quadrant; kh: K-half (interleaved 32s)
  int wm = quad >> 1, wn = quad & 1;
  int m0 = blockIdx.y * 128, n0 = blockIdx.x * 128;

  f32x4 acc[4][4];
  #pragma unroll
  for (int i=0;i<4;i++)
    #pragma unroll
    for (int j=0;j<4;j++) acc[i][j] = fzero();

  for (int kc = 0; kc < 1024; kc += 64){
    // --- stage 32 KB: 8 waves x 4 instrs x 1 KB. Source pre-swizzled so linear LDS
    // dest + XOR'd ds_read form the same involution (byte ^= ((row&7)<<4)).
    #pragma unroll
    for (int j = 0; j < 4; ++j){
      int ro = (wid*4 + j) * 1024;       // 0..31744
      int rr = ro & 16383;
      int r  = (rr >> 7) + (lane >> 3);  // row within 128-row tile
      int kq = ((lane & 7) ^ (r & 7)) << 3;   // swizzled k-chunk (8 elems)
      if (ro < 16384)
        gload_lds16(comb_mk + (size_t)(m0 + r)*Vn + kc + kq, (char*)As + rr);
      else
        gload_lds16(B2T    + (size_t)(n0 + r)*Vn + kc + kq, (char*)Bs + rr);
    }
    __syncthreads();
    // --- compute: wave's K-slice = kh*32 within the staged 64
    bh8 a[4], b[4];
    int kb = (kh << 5) + ((lane >> 4) << 3);
    #pragma unroll
    for (int mf=0; mf<4; ++mf){
      int row = wm*64 + mf*16 + (lane & 15);
      int byte = (row << 7) + (kb << 1);
      byte ^= (row & 7) << 4;
      a[mf] = *(const bh8*)((const char*)As + byte);
    }
    #pragma unroll
    for (int nf=0; nf<4; ++nf){
      int row = wn*64 + nf*16 + (lane & 15);
      int byte = (row << 7) + (kb << 1);
      byte ^= (row & 7) << 4;
      b[nf] = *(const bh8*)((const char*)Bs + byte);
    }
    #pragma unroll
    for (int mf=0; mf<4; ++mf)
      #pragma unroll
      for (int nf=0; nf<4; ++nf)
        acc[mf][nf] = __builtin_amdgcn_mfma_f32_16x16x32_bf16(a[mf], b[nf], acc[mf][nf], 0,0,0);
    __syncthreads();
  }

  // --- reduce K-halves
  if (kh){
    #pragma unroll
    for (int mf=0; mf<4; ++mf)
      #pragma unroll
      for (int nf=0; nf<4; ++nf) red[quad][mf*4+nf][lane] = acc[mf][nf];
  }
  __syncthreads();
  if (!kh){
    #pragma unroll
    for (int mf=0; mf<4; ++mf)
      #pragma unroll
      for (int nf=0; nf<4; ++nf) acc[mf][nf] += red[quad][mf*4+nf][lane];
    int b = (m0 >> 6) + wm;   // 64-row m-slices == batches
    #pragma unroll
    for (int mf=0; mf<4; ++mf){
      int cb = mf*16 + ((lane>>4)<<2);
      #pragma unroll
      for (int nf=0; nf<4; ++nf){
        int n = n0 + wn*64 + nf*16 + (lane & 15);
        int mat = n >> 10, w = n & 1023;
        unsigned short* dst = (mat ? x2c : x1c) + ((size_t)b*Vn + w)*Cn + cb;
        bh4 p;
        #pragma unroll
        for (int r=0;r<4;r++) p[r] = (short)f2bf(acc[mf][nf][r]);
        *(bh4*)dst = p;
      }
    }
  }
}

// Gates GEMM (Wperm @ [comb;x1;x2]) + fused LSTM pointwise + fused comb_{t+1}.
// 4 waves per block = 4 m-tiles of the same (v-tile, b): the comb/x1/x2 B-panels are
// read once into L1 and reused by all waves (was 4x L2 traffic as 4 separate blocks).
// h_t written to ys2[b][v][t][c] (t-minor) so k_proj's N-dim is linear n = v*24+t.
__global__ __launch_bounds__(256) void k_gates(const unsigned short* __restrict__ Wperm,
    const float* __restrict__ bperm,
    const unsigned short* __restrict__ combc_rd, const unsigned short* __restrict__ x1c,
    const unsigned short* __restrict__ x2c,
    float* __restrict__ cst, unsigned short* __restrict__ ys2,
    const unsigned short* __restrict__ xTc,
    unsigned short* __restrict__ combc_wr, unsigned short* __restrict__ combmk, int t){
  int lane = threadIdx.x & 63;
  int m0 = (threadIdx.x >> 6) * 64;           // wave = m-tile
  int v0 = blockIdx.x * 64, b = blockIdx.z;
  f32x4 acc[4][4];
  #pragma unroll
  for (int i=0;i<4;i++)
    #pragma unroll
    for (int j=0;j<4;j++) acc[i][j] = fzero();
  #pragma unroll
  for (int ki = 0; ki < 6; ++ki){
    int hop = ki >> 1, koff = (ki & 1) * 32;
    const unsigned short* hb = (hop == 0 ? combc_rd : hop == 1 ? x1c : x2c) + (size_t)b * Vn * Cn;
    bh8 a[4], bb[4];
    #pragma unroll
    for (int mf=0; mf<4; ++mf) a[mf]  = ld_frag(Wperm, Gn, m0, mf, hop*64 + koff, lane);
    #pragma unroll
    for (int nf=0; nf<4; ++nf) bb[nf] = ld_frag(hb, Cn, v0, nf, koff, lane);
    #pragma unroll
    for (int mf=0; mf<4; ++mf)
      #pragma unroll
      for (int nf=0; nf<4; ++nf)
        acc[mf][nf] = __builtin_amdgcn_mfma_f32_16x16x32_bf16(a[mf], bb[nf], acc[mf][nf], 0,0,0);
  }
  const bool wrc = (t + 1 < Tn);
  unsigned short* ysp = ys2 + (size_t)b * NT * Cn;            // [v*24 + t][c]
  const unsigned short* xnext = xTc + ((size_t)(t+1)*Bn + b) * Vn * Cn;
  unsigned short* ccp = combc_wr + (size_t)b * Vn * Cn;
  unsigned short* cmp = combmk   + (size_t)b * Cn * Vn;
  #pragma unroll
  for (int mf = 0; mf < 4; ++mf){
    int oprow = m0 + mf*16 + ((lane>>4)<<2);
    int c = oprow >> 2;
    float4 b4 = *(const float4*)(bperm + oprow);
    #pragma unroll
    for (int nf = 0; nf < 4; ++nf){
      int v = v0 + nf*16 + (lane & 15);
      float gi = sigm(acc[mf][nf][0] + b4.x);
      float gf = sigm(acc[mf][nf][1] + b4.y);
      float gg =      acc[mf][nf][2] + b4.z;     // cell gate used raw (no tanh) per reference
      float go = sigm(acc[mf][nf][3] + b4.w);
      size_t ci = ((size_t)b*Cn + c)*Vn + v;
      float cy = gf * cst[ci] + gi * gg;
      cst[ci] = cy;
      unsigned short hb16 = f2bf(go * tanhfast(cy));
      ysp[((size_t)v*Tn + t)*Cn + c] = hb16;
      if (wrc){
        float s = bf2f(hb16) + bf2f(xnext[(size_t)v*Cn + c]);
        unsigned short cb = f2bf(s);
        ccp[(size_t)v*Cn + c] = cb;
        cmp[(size_t)c*Vn + v] = cb;
      }
    }
  }
}

// Projection as MFMA GEMM per batch: out[b][o][n] = sum_c (Whi+Wlo)[o][c] * ys2[b][n][c] + bo[o],
// with n = v*24 + t linear -> fully coalesced loads AND stores (fixes the 2x write amplification).
__global__ __launch_bounds__(256) void k_proj(const unsigned short* __restrict__ ys2,
    const unsigned short* __restrict__ Whi, const unsigned short* __restrict__ Wlo,
    const float* __restrict__ bout, float* __restrict__ out){
  int lane = threadIdx.x & 63, wid = threadIdx.x >> 6;
  int b = blockIdx.y;
  int n0 = blockIdx.x * 256 + wid * 64;
  const unsigned short* yb = ys2 + (size_t)b * NT * Cn;
  f32x4 acc[4][4];
  #pragma unroll
  for (int i=0;i<4;i++)
    #pragma unroll
    for (int j=0;j<4;j++) acc[i][j] = fzero();
  bh8 bfrag[2][4];
  #pragma unroll
  for (int ks=0; ks<2; ++ks)
    #pragma unroll
    for (int nf=0; nf<4; ++nf)
      bfrag[ks][nf] = ld_frag(yb, Cn, n0, nf, ks*32, lane);
  #pragma unroll
  for (int hl=0; hl<2; ++hl){
    const unsigned short* W = hl ? Wlo : Whi;
    #pragma unroll
    for (int ks=0; ks<2; ++ks){
      bh8 a[4];
      #pragma unroll
      for (int mf=0; mf<4; ++mf) a[mf] = ld_frag(W, Cn, 0, mf, ks*32, lane);
      #pragma unroll
      for (int mf=0; mf<4; ++mf)
        #pragma unroll
        for (int nf=0; nf<4; ++nf)
          acc[mf][nf] = __builtin_amdgcn_mfma_f32_16x16x32_bf16(a[mf], bfrag[ks][nf], acc[mf][nf], 0,0,0);
    }
  }
  #pragma unroll
  for (int mf=0; mf<4; ++mf){
    int ob = mf*16 + ((lane>>4)<<2);
    float bo0 = bout[ob+0], bo1 = bout[ob+1], bo2 = bout[ob+2], bo3 = bout[ob+3];
    #pragma unroll
    for (int nf=0; nf<4; ++nf){
      int n = n0 + nf*16 + (lane & 15);
      float* op = out + ((size_t)(b*64 + ob) * NT + n);
      op[0*NT] = acc[mf][nf][0] + bo0;
      op[1*NT] = acc[mf][nf][1] + bo1;
      op[2*NT] = acc[mf][nf][2] + bo2;
      op[3*NT] = acc[mf][nf][3] + bo3;
    }
  }
}

// ---------------------------------------------------------------------------
extern "C" void kernel_launch(void* const* d_in, const int* in_sizes, int n_in,
                              void* d_out, int out_size, void* d_ws, size_t ws_size,
                              hipStream_t stream){
  const float* x   = (const float*)d_in[0];
  const float* A   = (const float*)d_in[1];
  const float* Wg  = (const float*)d_in[2];
  const float* bg  = (const float*)d_in[3];
  const float* Wo  = (const float*)d_in[4];
  const float* bo  = (const float*)d_in[5];
  float* out = (float*)d_out;

  char* ws = (char*)d_ws;
  size_t off = 0;
  auto alloc = [&](size_t bytes)->char*{
    char* p = ws + off; off = (off + bytes + 255) & ~(size_t)255; return p;
  };
  const size_t PLANE = (size_t)Bn*Vn*Cn;   // elements per (b,v,c) plane
  unsigned short* Abf    = (unsigned short*)alloc((size_t)Vn*Vn*2);
  unsigned short* B2T    = (unsigned short*)alloc((size_t)2*Vn*Vn*2);   // [A^T; A2^T]
  float*          A2f    = (float*)         alloc((size_t)Vn*Vn*4);
  unsigned short* Wperm  = (unsigned short*)alloc((size_t)O4*Gn*2);
  float*          bperm  = (float*)         alloc((size_t)O4*4);
  unsigned short* Whi    = (unsigned short*)alloc((size_t)Cn*Cn*2);
  unsigned short* Wlo    = (unsigned short*)alloc((size_t)Cn*Cn*2);
  unsigned short* xTc    = (unsigned short*)alloc((size_t)Tn*PLANE*2);
  unsigned short* ys2    = (unsigned short*)alloc((size_t)Bn*NT*Cn*2);  // [b][v*24+t][c]
  unsigned short* combc  = (unsigned short*)alloc(2*PLANE*2);           // double-buffered
  unsigned short* combmk = (unsigned short*)alloc(PLANE*2);
  unsigned short* x1c    = (unsigned short*)alloc(PLANE*2);
  unsigned short* x2c    = (unsigned short*)alloc(PLANE*2);
  float*          cst    = (float*)         alloc(PLANE*4);
  (void)in_sizes; (void)n_in; (void)out_size; (void)ws_size;

  hipMemsetAsync(cst, 0, PLANE*4, stream);

  k_prep_w<<<1, 256, 0, stream>>>(Wg, bg, Wperm, bperm);
  k_prep_wo<<<16, 256, 0, stream>>>(Wo, Whi, Wlo);
  k_transq<<<dim3(16,16), 256, 0, stream>>>(A, Abf, B2T);                 // rows 0..1023 = A^T
  k_gemm_a2<<<dim3(16,16), 256, 0, stream>>>(Abf, B2T, A2f);
  k_transq<<<dim3(16,16), 256, 0, stream>>>(A2f, (unsigned short*)nullptr,
                                            B2T + (size_t)Vn*Vn);         // rows 1024.. = A2^T
  k_transpose_x<<<dim3(256,32), 256, 0, stream>>>(x, xTc);

  // t=0: h0 == 0 so comb = x_0
  k_comb0<<<dim3(16,Bn), 256, 0, stream>>>(xTc, combc, combmk);

  for (int t = 0; t < Tn; ++t){
    k_dual2<<<dim3(16,16),  512, 0, stream>>>(combmk, B2T, x1c, x2c);
    k_gates<<<dim3(16,1,Bn), 256, 0, stream>>>(Wperm, bperm,
                combc + (size_t)(t & 1) * PLANE, x1c, x2c, cst, ys2,
                xTc, combc + (size_t)((t + 1) & 1) * PLANE, combmk, t);
  }
  k_proj<<<dim3(96,32), 256, 0, stream>>>(ys2, Whi, Wlo, bo, out);
}

// Round 3
// 1356.934 us; speedup vs baseline: 1.5265x; 1.1912x over previous
//
#include <hip/hip_runtime.h>
#include <stdint.h>

// Problem constants (fixed by the reference)
#define Bn 32
#define Cn 64
#define Vn 1024
#define Tn 24
#define Gn 192   // 3*C
#define O4 256   // 4*C
#define NT 24576 // Vn*Tn (linear n-dim of the projection GEMM)

typedef __attribute__((ext_vector_type(8))) short bh8;   // 8 x bf16 (MFMA A/B frag)
typedef __attribute__((ext_vector_type(4))) short bh4;   // 4 x bf16 packed store
typedef __attribute__((ext_vector_type(4))) float f32x4; // MFMA C/D frag

__device__ __forceinline__ float bf2f(unsigned short u){
  union { unsigned int i; float f; } x; x.i = ((unsigned int)u) << 16; return x.f;
}
__device__ __forceinline__ unsigned short f2bf(float f){
  union { float f; unsigned int i; } x; x.f = f;
  unsigned int u = x.i;
  return (unsigned short)((u + 0x7fffu + ((u >> 16) & 1u)) >> 16); // RNE
}
__device__ __forceinline__ float sigm(float x){ return 1.f/(1.f+__expf(-x)); }
__device__ __forceinline__ float tanhfast(float x){ return 1.f - 2.f/(__expf(2.f*x)+1.f); }
__device__ __forceinline__ f32x4 fzero(){ f32x4 z = {0.f,0.f,0.f,0.f}; return z; }

// async global->LDS, 16B per lane; LDS dest is wave-uniform base + lane*16
__device__ __forceinline__ void gload_lds16(const void* g, void* l){
  __builtin_amdgcn_global_load_lds(
      (const __attribute__((address_space(1))) void*)g,
      (__attribute__((address_space(3))) void*)l, 16, 0, 0);
}

// MFMA 16x16x32 frag loader (TN convention: both operands row-major with k contiguous).
// lane l holds X[idx = r0 + mf*16 + (l&15)][k = k0 + (l>>4)*8 + j], j=0..7  -> one b128 load.
__device__ __forceinline__ bh8 ld_frag(const unsigned short* base, int stride, int r0, int mf,
                                       int k0, int lane){
  int r  = r0 + mf*16 + (lane & 15);
  int kk = k0 + ((lane >> 4) << 3);
  return *(const bh8*)(base + (size_t)r * stride + kk);
}

// ---------------------------------------------------------------------------
// Prep: permute W_gout rows to o' = c*4 + gate, quantize to bf16; permute bias.
__global__ void k_prep_w(const float* __restrict__ Wg, const float* __restrict__ bg,
                         unsigned short* __restrict__ Wperm, float* __restrict__ bperm){
  int op = threadIdx.x;              // 0..255 = o'
  int gate = op & 3, c = op >> 2;
  int oo = gate * 64 + c;            // original row in W_gout
  for (int g = 0; g < Gn; ++g)
    Wperm[op * Gn + g] = f2bf(Wg[(size_t)oo * Gn + g]);
  bperm[op] = bg[oo];
}

// Split W_out (64x64 fp32) into bf16 hi + lo so the projection MFMA keeps ~fp32 accuracy.
__global__ void k_prep_wo(const float* __restrict__ Wo, unsigned short* __restrict__ Whi,
                          unsigned short* __restrict__ Wlo){
  int e = blockIdx.x * 256 + threadIdx.x;   // 4096 total
  float w = Wo[e];
  unsigned short hi = f2bf(w);
  Whi[e] = hi;
  Wlo[e] = f2bf(w - bf2f(hi));
}

// Quantize + transpose a 1024x1024 fp32 matrix: dst (optional) = bf16(src), dstT = bf16(src^T)
__global__ void k_transq(const float* __restrict__ src, unsigned short* dst,
                         unsigned short* __restrict__ dstT){
  __shared__ float tile[64][65];
  int j0 = blockIdx.x * 64, i0 = blockIdx.y * 64;
  for (int e = threadIdx.x; e < 4096; e += 256){
    int r = e >> 6, col = e & 63;
    float v = src[(size_t)(i0 + r) * Vn + j0 + col];
    if (dst) dst[(size_t)(i0 + r) * Vn + j0 + col] = f2bf(v);
    tile[r][col] = v;
  }
  __syncthreads();
  for (int e = threadIdx.x; e < 4096; e += 256){
    int r = e >> 6, col = e & 63;
    dstT[(size_t)(j0 + r) * Vn + i0 + col] = f2bf(tile[col][r]);
  }
}

// A2 = A @ A  (bf16 MFMA, fp32 out). 4 waves split K into quarters; LDS reduce.
__global__ __launch_bounds__(256) void k_gemm_a2(const unsigned short* __restrict__ Ab,
                                                 const unsigned short* __restrict__ ATb,
                                                 float* __restrict__ A2){
  __shared__ f32x4 red[3][4][4][64];   // 48 KB
  int lane = threadIdx.x & 63;
  int wv   = threadIdx.x >> 6;         // 0..3: K-quarter
  int n0 = blockIdx.x * 64, m0 = blockIdx.y * 64;
  f32x4 acc[4][4];
  #pragma unroll
  for (int i=0;i<4;i++)
    #pragma unroll
    for (int j=0;j<4;j++) acc[i][j] = fzero();
  int kbeg = wv * 256;
  #pragma unroll 2
  for (int k = kbeg; k < kbeg + 256; k += 32){
    bh8 a[4], b[4];
    #pragma unroll
    for (int mf=0; mf<4; ++mf) a[mf] = ld_frag(Ab, Vn, m0, mf, k, lane);
    #pragma unroll
    for (int nf=0; nf<4; ++nf) b[nf] = ld_frag(ATb, Vn, n0, nf, k, lane);
    #pragma unroll
    for (int mf=0; mf<4; ++mf)
      #pragma unroll
      for (int nf=0; nf<4; ++nf)
        acc[mf][nf] = __builtin_amdgcn_mfma_f32_16x16x32_bf16(a[mf], b[nf], acc[mf][nf], 0,0,0);
  }
  if (wv){
    #pragma unroll
    for (int mf=0; mf<4; ++mf)
      #pragma unroll
      for (int nf=0; nf<4; ++nf) red[wv-1][mf][nf][lane] = acc[mf][nf];
  }
  __syncthreads();
  if (!wv){
    #pragma unroll
    for (int mf=0; mf<4; ++mf)
      #pragma unroll
      for (int nf=0; nf<4; ++nf)
        #pragma unroll
        for (int q=0;q<3;q++) acc[mf][nf] += red[q][mf][nf][lane];
    #pragma unroll
    for (int mf=0; mf<4; ++mf){
      int rb = m0 + mf*16 + ((lane>>4)<<2);
      #pragma unroll
      for (int nf=0; nf<4; ++nf){
        int cc = n0 + nf*16 + (lane&15);
        #pragma unroll
        for (int r=0;r<4;r++) A2[(size_t)(rb+r)*Vn + cc] = acc[mf][nf][r];
      }
    }
  }
}

// x (B,C,V,T) fp32 -> xTc[t][b][v][c] bf16 (c contiguous)
__global__ void k_transpose_x(const float* __restrict__ x, unsigned short* __restrict__ xT){
  int tid = threadIdx.x;
  int c = tid & 63, vl = tid >> 6;
  int b = blockIdx.y;
  int v = blockIdx.x * 4 + vl;
  const float* xp = x + ((size_t)(b * Cn + c) * Vn + v) * Tn;
  float vals[24];
  #pragma unroll
  for (int q = 0; q < 6; ++q){
    float4 f = *(const float4*)(xp + q*4);
    vals[q*4+0]=f.x; vals[q*4+1]=f.y; vals[q*4+2]=f.z; vals[q*4+3]=f.w;
  }
  #pragma unroll
  for (int t = 0; t < Tn; ++t)
    xT[((size_t)(t*Bn + b) * Vn + v) * Cn + c] = f2bf(vals[t]);
}

// t=0 comb: h0 == 0 so comb = x_0. Writes combc[b][v][c] and combmk[b*C+c][v].
__global__ __launch_bounds__(256) void k_comb0(const unsigned short* __restrict__ xTc,
    unsigned short* __restrict__ combc, unsigned short* __restrict__ combmk){
  __shared__ unsigned short tile[64][65];
  int b = blockIdx.y, v0 = blockIdx.x * 64;
  const unsigned short* xp = xTc + (size_t)b * Vn * Cn;   // plane t=0
  for (int e = threadIdx.x; e < 4096; e += 256){
    int vl = e >> 6, c = e & 63;
    size_t o = (size_t)(v0 + vl) * Cn + c;
    unsigned short s = xp[o];
    combc[(size_t)b*Vn*Cn + o] = s;
    tile[vl][c] = s;
  }
  __syncthreads();
  for (int e = threadIdx.x; e < 4096; e += 256){
    int c = e >> 6, vl = e & 63;
    combmk[((size_t)b*Cn + c)*Vn + v0 + vl] = tile[vl][c];
  }
}

// ---------------------------------------------------------------------------
// Fully fused recurrent step. Block = (w-tile of 64, batch b). 4 waves.
// Phase 1 (dual GEMM): x1/x2[c=0..63][w-tile] over K=1024, waves = (mat, K-half),
//   4x4 frags each (LDS-BW-balanced 0.5 ds_reads/MFMA). Staging: As 8KB + Bs 16KB,
//   global_load_lds(16B) with XOR swizzle (linear LDS dest + pre-swizzled source).
// Phase 2: K-half reduce via 32KB LDS; results written bf16 to LDS xs[2][64w][64c]
//   (swizzled) -- x1/x2 never touch global memory.
// Phase 3 (gates GEMM): Wperm(256x192) @ [comb;x1;x2](192 x 64w); hop0 B from global
//   combc, hop1/2 B from LDS xs. Wave = 64-row m-tile.
// Phase 4: LSTM pointwise + write h_t (ys2), c_t (cst), comb_{t+1} (both layouts).
// Cross-step hazard: comb buffers are double-buffered (read t&1, write (t+1)&1);
// the per-t launch boundary is the producer/consumer sync.
__global__ __launch_bounds__(256) void f_step(
    const unsigned short* __restrict__ combmk_rd,   // [b][c][v] bf16
    const unsigned short* __restrict__ B2T,         // rows 0..1023 A^T, 1024..2047 A2^T
    const unsigned short* __restrict__ Wperm, const float* __restrict__ bperm,
    const unsigned short* __restrict__ combc_rd,    // [b][v][c]
    float* __restrict__ cst, unsigned short* __restrict__ ys2,
    const unsigned short* __restrict__ xTc,
    unsigned short* __restrict__ combc_wr, unsigned short* __restrict__ combmk_wr,
    int t){
  __shared__ char smem[24576];       // phase1: As[64][64] @0, Bs[128][64] @8192; phase3: xs[2][64][64]
  __shared__ f32x4 red[2][16][64];   // 32 KB K-half reduce
  int lane = threadIdx.x & 63, wid = threadIdx.x >> 6;
  int mat = wid & 1, kh = wid >> 1;  // wave role in phase 1
  int n0 = blockIdx.x * 64;          // w-tile
  int b  = blockIdx.y;
  const unsigned short* Arow = combmk_rd + (size_t)b * Cn * Vn;

  f32x4 acc[4][4];
  #pragma unroll
  for (int i=0;i<4;i++)
    #pragma unroll
    for (int j=0;j<4;j++) acc[i][j] = fzero();

  // ---- Phase 1: dual GEMM over K=1024, BK=64 staged ----
  for (int kc = 0; kc < 1024; kc += 64){
    #pragma unroll
    for (int j = 0; j < 6; ++j){
      int idx = wid*6 + j;                 // 24 x 1KB chunks (8 As + 16 Bs)
      const unsigned short* src;
      int r;
      if (idx < 8){
        r = idx*8 + (lane >> 3);           // As local row 0..63 (= c)
        src = Arow + (size_t)r * Vn;
      } else {
        int rb = (idx - 8)*8 + (lane >> 3);   // Bs local row 0..127
        int grow = (rb < 64) ? (n0 + rb) : (Vn + n0 + rb - 64);
        r = rb;
        src = B2T + (size_t)grow * Vn;
      }
      int kq = ((lane & 7) ^ (r & 7)) << 3;   // pre-swizzled source granule
      gload_lds16(src + kc + kq, smem + idx*1024);
    }
    __syncthreads();
    int kb = (kh << 5) + ((lane >> 4) << 3);  // k within staged 64
    bh8 a[4], bb[4];
    #pragma unroll
    for (int mf=0; mf<4; ++mf){
      int row = mf*16 + (lane & 15);
      int byte = (row << 7) + (kb << 1);  byte ^= (row & 7) << 4;
      a[mf] = *(const bh8*)(smem + byte);
    }
    #pragma unroll
    for (int nf=0; nf<4; ++nf){
      int rb = mat*64 + nf*16 + (lane & 15);
      int byte = 8192 + (rb << 7) + (kb << 1);  byte ^= (rb & 7) << 4;
      bb[nf] = *(const bh8*)(smem + byte);
    }
    #pragma unroll
    for (int mf=0; mf<4; ++mf)
      #pragma unroll
      for (int nf=0; nf<4; ++nf)
        acc[mf][nf] = __builtin_amdgcn_mfma_f32_16x16x32_bf16(a[mf], bb[nf], acc[mf][nf], 0,0,0);
    __syncthreads();
  }

  // ---- Phase 2: K-half reduce, then x1/x2 -> LDS xs (bf16, swizzled) ----
  if (kh){
    #pragma unroll
    for (int mf=0; mf<4; ++mf)
      #pragma unroll
      for (int nf=0; nf<4; ++nf) red[mat][mf*4+nf][lane] = acc[mf][nf];
  }
  __syncthreads();
  if (!kh){
    #pragma unroll
    for (int mf=0; mf<4; ++mf)
      #pragma unroll
      for (int nf=0; nf<4; ++nf){
        acc[mf][nf] += red[mat][mf*4+nf][lane];
        int c0 = mf*16 + ((lane >> 4) << 2);
        int w  = nf*16 + (lane & 15);
        int byte = mat*8192 + (w << 7) + (c0 << 1);  byte ^= (w & 7) << 4;
        bh4 p;
        #pragma unroll
        for (int r=0;r<4;r++) p[r] = (short)f2bf(acc[mf][nf][r]);
        *(bh4*)(smem + byte) = p;
      }
  }
  __syncthreads();

  // ---- Phase 3: gates GEMM. Wave = m-tile (64 rows of o' = c*4+gate) ----
  int m0 = wid * 64;
  f32x4 g[4][4];
  #pragma unroll
  for (int i=0;i<4;i++)
    #pragma unroll
    for (int j=0;j<4;j++) g[i][j] = fzero();
  const unsigned short* cb = combc_rd + (size_t)b * Vn * Cn;
  #pragma unroll
  for (int ki = 0; ki < 6; ++ki){
    int hop = ki >> 1, koff = (ki & 1) * 32;
    bh8 a[4], bb[4];
    #pragma unroll
    for (int mf=0; mf<4; ++mf) a[mf] = ld_frag(Wperm, Gn, m0, mf, hop*64 + koff, lane);
    if (hop == 0){
      #pragma unroll
      for (int nf=0; nf<4; ++nf) bb[nf] = ld_frag(cb, Cn, n0, nf, koff, lane);
    } else {
      #pragma unroll
      for (int nf=0; nf<4; ++nf){
        int w = nf*16 + (lane & 15);
        int kk = koff + ((lane >> 4) << 3);
        int byte = (hop-1)*8192 + (w << 7) + (kk << 1);  byte ^= (w & 7) << 4;
        bb[nf] = *(const bh8*)(smem + byte);
      }
    }
    #pragma unroll
    for (int mf=0; mf<4; ++mf)
      #pragma unroll
      for (int nf=0; nf<4; ++nf)
        g[mf][nf] = __builtin_amdgcn_mfma_f32_16x16x32_bf16(a[mf], bb[nf], g[mf][nf], 0,0,0);
  }

  // ---- Phase 4: LSTM pointwise + state/comb writes ----
  const bool wrc = (t + 1 < Tn);
  unsigned short* ysp = ys2 + (size_t)b * NT * Cn;                 // [v*24 + t][c]
  const unsigned short* xnext = xTc + ((size_t)(t+1)*Bn + b) * (size_t)Vn * Cn;
  unsigned short* ccp = combc_wr  + (size_t)b * Vn * Cn;
  unsigned short* cmp = combmk_wr + (size_t)b * Cn * Vn;
  #pragma unroll
  for (int mf = 0; mf < 4; ++mf){
    int oprow = m0 + mf*16 + ((lane>>4)<<2);
    int c = oprow >> 2;
    float4 b4 = *(const float4*)(bperm + oprow);
    #pragma unroll
    for (int nf = 0; nf < 4; ++nf){
      int v = n0 + nf*16 + (lane & 15);
      float gi = sigm(g[mf][nf][0] + b4.x);
      float gf = sigm(g[mf][nf][1] + b4.y);
      float gg =      g[mf][nf][2] + b4.z;     // cell gate used raw (no tanh) per reference
      float go = sigm(g[mf][nf][3] + b4.w);
      size_t ci = ((size_t)b*Cn + c)*Vn + v;
      float cy = gf * cst[ci] + gi * gg;
      cst[ci] = cy;
      unsigned short hb16 = f2bf(go * tanhfast(cy));
      ysp[((size_t)v*Tn + t)*Cn + c] = hb16;
      if (wrc){
        float s = bf2f(hb16) + bf2f(xnext[(size_t)v*Cn + c]);
        unsigned short cbv = f2bf(s);
        ccp[(size_t)v*Cn + c] = cbv;
        cmp[(size_t)c*Vn + v] = cbv;
      }
    }
  }
}

// Projection as MFMA GEMM per batch: out[b][o][n] = sum_c (Whi+Wlo)[o][c] * ys2[b][n][c] + bo[o],
// with n = v*24 + t linear -> fully coalesced loads AND stores.
__global__ __launch_bounds__(256) void k_proj(const unsigned short* __restrict__ ys2,
    const unsigned short* __restrict__ Whi, const unsigned short* __restrict__ Wlo,
    const float* __restrict__ bout, float* __restrict__ out){
  int lane = threadIdx.x & 63, wid = threadIdx.x >> 6;
  int b = blockIdx.y;
  int n0 = blockIdx.x * 256 + wid * 64;
  const unsigned short* yb = ys2 + (size_t)b * NT * Cn;
  f32x4 acc[4][4];
  #pragma unroll
  for (int i=0;i<4;i++)
    #pragma unroll
    for (int j=0;j<4;j++) acc[i][j] = fzero();
  bh8 bfrag[2][4];
  #pragma unroll
  for (int ks=0; ks<2; ++ks)
    #pragma unroll
    for (int nf=0; nf<4; ++nf)
      bfrag[ks][nf] = ld_frag(yb, Cn, n0, nf, ks*32, lane);
  #pragma unroll
  for (int hl=0; hl<2; ++hl){
    const unsigned short* W = hl ? Wlo : Whi;
    #pragma unroll
    for (int ks=0; ks<2; ++ks){
      bh8 a[4];
      #pragma unroll
      for (int mf=0; mf<4; ++mf) a[mf] = ld_frag(W, Cn, 0, mf, ks*32, lane);
      #pragma unroll
      for (int mf=0; mf<4; ++mf)
        #pragma unroll
        for (int nf=0; nf<4; ++nf)
          acc[mf][nf] = __builtin_amdgcn_mfma_f32_16x16x32_bf16(a[mf], bfrag[ks][nf], acc[mf][nf], 0,0,0);
    }
  }
  #pragma unroll
  for (int mf=0; mf<4; ++mf){
    int ob = mf*16 + ((lane>>4)<<2);
    float bo0 = bout[ob+0], bo1 = bout[ob+1], bo2 = bout[ob+2], bo3 = bout[ob+3];
    #pragma unroll
    for (int nf=0; nf<4; ++nf){
      int n = n0 + nf*16 + (lane & 15);
      float* op = out + ((size_t)(b*64 + ob) * NT + n);
      op[0*NT] = acc[mf][nf][0] + bo0;
      op[1*NT] = acc[mf][nf][1] + bo1;
      op[2*NT] = acc[mf][nf][2] + bo2;
      op[3*NT] = acc[mf][nf][3] + bo3;
    }
  }
}

// ---------------------------------------------------------------------------
extern "C" void kernel_launch(void* const* d_in, const int* in_sizes, int n_in,
                              void* d_out, int out_size, void* d_ws, size_t ws_size,
                              hipStream_t stream){
  const float* x   = (const float*)d_in[0];
  const float* A   = (const float*)d_in[1];
  const float* Wg  = (const float*)d_in[2];
  const float* bg  = (const float*)d_in[3];
  const float* Wo  = (const float*)d_in[4];
  const float* bo  = (const float*)d_in[5];
  float* out = (float*)d_out;

  char* ws = (char*)d_ws;
  size_t off = 0;
  auto alloc = [&](size_t bytes)->char*{
    char* p = ws + off; off = (off + bytes + 255) & ~(size_t)255; return p;
  };
  const size_t PLANE = (size_t)Bn*Vn*Cn;   // elements per (b,v,c) plane
  unsigned short* Abf    = (unsigned short*)alloc((size_t)Vn*Vn*2);
  unsigned short* B2T    = (unsigned short*)alloc((size_t)2*Vn*Vn*2);   // [A^T; A2^T]
  float*          A2f    = (float*)         alloc((size_t)Vn*Vn*4);
  unsigned short* Wperm  = (unsigned short*)alloc((size_t)O4*Gn*2);
  float*          bperm  = (float*)         alloc((size_t)O4*4);
  unsigned short* Whi    = (unsigned short*)alloc((size_t)Cn*Cn*2);
  unsigned short* Wlo    = (unsigned short*)alloc((size_t)Cn*Cn*2);
  unsigned short* xTc    = (unsigned short*)alloc((size_t)Tn*PLANE*2);
  unsigned short* ys2    = (unsigned short*)alloc((size_t)Bn*NT*Cn*2);  // [b][v*24+t][c]
  unsigned short* combc  = (unsigned short*)alloc(2*PLANE*2);           // double-buffered
  unsigned short* combmk = (unsigned short*)alloc(2*PLANE*2);           // double-buffered
  float*          cst    = (float*)         alloc(PLANE*4);
  (void)in_sizes; (void)n_in; (void)out_size; (void)ws_size;

  hipMemsetAsync(cst, 0, PLANE*4, stream);

  k_prep_w<<<1, 256, 0, stream>>>(Wg, bg, Wperm, bperm);
  k_prep_wo<<<16, 256, 0, stream>>>(Wo, Whi, Wlo);
  k_transq<<<dim3(16,16), 256, 0, stream>>>(A, Abf, B2T);                 // rows 0..1023 = A^T
  k_gemm_a2<<<dim3(16,16), 256, 0, stream>>>(Abf, B2T, A2f);
  k_transq<<<dim3(16,16), 256, 0, stream>>>(A2f, (unsigned short*)nullptr,
                                            B2T + (size_t)Vn*Vn);         // rows 1024.. = A2^T
  k_transpose_x<<<dim3(256,32), 256, 0, stream>>>(x, xTc);

  // t=0: h0 == 0 so comb = x_0 (fills buffer 0 of both comb layouts)
  k_comb0<<<dim3(16,Bn), 256, 0, stream>>>(xTc, combc, combmk);

  for (int t = 0; t < Tn; ++t){
    f_step<<<dim3(16,Bn), 256, 0, stream>>>(
        combmk + (size_t)(t & 1) * PLANE, B2T, Wperm, bperm,
        combc  + (size_t)(t & 1) * PLANE, cst, ys2, xTc,
        combc  + (size_t)((t + 1) & 1) * PLANE,
        combmk + (size_t)((t + 1) & 1) * PLANE, t);
  }
  k_proj<<<dim3(96,32), 256, 0, stream>>>(ys2, Whi, Wlo, bo, out);
}

// Round 4
// 1167.717 us; speedup vs baseline: 1.7739x; 1.1620x over previous
//
#include <hip/hip_runtime.h>
#include <stdint.h>

// Problem constants (fixed by the reference)
#define Bn 32
#define Cn 64
#define Vn 1024
#define Tn 24
#define Gn 192   // 3*C
#define O4 256   // 4*C
#define NT 24576 // Vn*Tn (linear n-dim of the projection GEMM)

typedef __attribute__((ext_vector_type(8))) short bh8;   // 8 x bf16 (MFMA A/B frag)
typedef __attribute__((ext_vector_type(4))) short bh4;   // 4 x bf16 packed store
typedef __attribute__((ext_vector_type(4))) float f32x4; // MFMA C/D frag

__device__ __forceinline__ float bf2f(unsigned short u){
  union { unsigned int i; float f; } x; x.i = ((unsigned int)u) << 16; return x.f;
}
__device__ __forceinline__ unsigned short f2bf(float f){
  union { float f; unsigned int i; } x; x.f = f;
  unsigned int u = x.i;
  return (unsigned short)((u + 0x7fffu + ((u >> 16) & 1u)) >> 16); // RNE
}
__device__ __forceinline__ float sigm(float x){ return 1.f/(1.f+__expf(-x)); }
__device__ __forceinline__ float tanhfast(float x){ return 1.f - 2.f/(__expf(2.f*x)+1.f); }
__device__ __forceinline__ f32x4 fzero(){ f32x4 z = {0.f,0.f,0.f,0.f}; return z; }

// async global->LDS, 16B per lane; LDS dest is wave-uniform base + lane*16
__device__ __forceinline__ void gload_lds16(const void* g, void* l){
  __builtin_amdgcn_global_load_lds(
      (const __attribute__((address_space(1))) void*)g,
      (__attribute__((address_space(3))) void*)l, 16, 0, 0);
}

// MFMA 16x16x32 frag loader (TN convention: both operands row-major with k contiguous).
__device__ __forceinline__ bh8 ld_frag(const unsigned short* base, int stride, int r0, int mf,
                                       int k0, int lane){
  int r  = r0 + mf*16 + (lane & 15);
  int kk = k0 + ((lane >> 4) << 3);
  return *(const bh8*)(base + (size_t)r * stride + kk);
}

// ---------------------------------------------------------------------------
__global__ void k_prep_w(const float* __restrict__ Wg, const float* __restrict__ bg,
                         unsigned short* __restrict__ Wperm, float* __restrict__ bperm){
  int op = threadIdx.x;              // 0..255 = o'
  int gate = op & 3, c = op >> 2;
  int oo = gate * 64 + c;            // original row in W_gout
  for (int g = 0; g < Gn; ++g)
    Wperm[op * Gn + g] = f2bf(Wg[(size_t)oo * Gn + g]);
  bperm[op] = bg[oo];
}

__global__ void k_prep_wo(const float* __restrict__ Wo, unsigned short* __restrict__ Whi,
                          unsigned short* __restrict__ Wlo){
  int e = blockIdx.x * 256 + threadIdx.x;   // 4096 total
  float w = Wo[e];
  unsigned short hi = f2bf(w);
  Whi[e] = hi;
  Wlo[e] = f2bf(w - bf2f(hi));
}

__global__ void k_transq(const float* __restrict__ src, unsigned short* dst,
                         unsigned short* __restrict__ dstT){
  __shared__ float tile[64][65];
  int j0 = blockIdx.x * 64, i0 = blockIdx.y * 64;
  for (int e = threadIdx.x; e < 4096; e += 256){
    int r = e >> 6, col = e & 63;
    float v = src[(size_t)(i0 + r) * Vn + j0 + col];
    if (dst) dst[(size_t)(i0 + r) * Vn + j0 + col] = f2bf(v);
    tile[r][col] = v;
  }
  __syncthreads();
  for (int e = threadIdx.x; e < 4096; e += 256){
    int r = e >> 6, col = e & 63;
    dstT[(size_t)(j0 + r) * Vn + i0 + col] = f2bf(tile[col][r]);
  }
}

__global__ __launch_bounds__(256) void k_gemm_a2(const unsigned short* __restrict__ Ab,
                                                 const unsigned short* __restrict__ ATb,
                                                 float* __restrict__ A2){
  __shared__ f32x4 red[3][4][4][64];   // 48 KB
  int lane = threadIdx.x & 63;
  int wv   = threadIdx.x >> 6;         // 0..3: K-quarter
  int n0 = blockIdx.x * 64, m0 = blockIdx.y * 64;
  f32x4 acc[4][4];
  #pragma unroll
  for (int i=0;i<4;i++)
    #pragma unroll
    for (int j=0;j<4;j++) acc[i][j] = fzero();
  int kbeg = wv * 256;
  #pragma unroll 2
  for (int k = kbeg; k < kbeg + 256; k += 32){
    bh8 a[4], b[4];
    #pragma unroll
    for (int mf=0; mf<4; ++mf) a[mf] = ld_frag(Ab, Vn, m0, mf, k, lane);
    #pragma unroll
    for (int nf=0; nf<4; ++nf) b[nf] = ld_frag(ATb, Vn, n0, nf, k, lane);
    #pragma unroll
    for (int mf=0; mf<4; ++mf)
      #pragma unroll
      for (int nf=0; nf<4; ++nf)
        acc[mf][nf] = __builtin_amdgcn_mfma_f32_16x16x32_bf16(a[mf], b[nf], acc[mf][nf], 0,0,0);
  }
  if (wv){
    #pragma unroll
    for (int mf=0; mf<4; ++mf)
      #pragma unroll
      for (int nf=0; nf<4; ++nf) red[wv-1][mf][nf][lane] = acc[mf][nf];
  }
  __syncthreads();
  if (!wv){
    #pragma unroll
    for (int mf=0; mf<4; ++mf)
      #pragma unroll
      for (int nf=0; nf<4; ++nf)
        #pragma unroll
        for (int q=0;q<3;q++) acc[mf][nf] += red[q][mf][nf][lane];
    #pragma unroll
    for (int mf=0; mf<4; ++mf){
      int rb = m0 + mf*16 + ((lane>>4)<<2);
      #pragma unroll
      for (int nf=0; nf<4; ++nf){
        int cc = n0 + nf*16 + (lane&15);
        #pragma unroll
        for (int r=0;r<4;r++) A2[(size_t)(rb+r)*Vn + cc] = acc[mf][nf][r];
      }
    }
  }
}

// x (B,C,V,T) fp32 -> xTc[t][b][v][c] bf16 (c contiguous)
__global__ void k_transpose_x(const float* __restrict__ x, unsigned short* __restrict__ xT){
  int tid = threadIdx.x;
  int c = tid & 63, vl = tid >> 6;
  int b = blockIdx.y;
  int v = blockIdx.x * 4 + vl;
  const float* xp = x + ((size_t)(b * Cn + c) * Vn + v) * Tn;
  float vals[24];
  #pragma unroll
  for (int q = 0; q < 6; ++q){
    float4 f = *(const float4*)(xp + q*4);
    vals[q*4+0]=f.x; vals[q*4+1]=f.y; vals[q*4+2]=f.z; vals[q*4+3]=f.w;
  }
  #pragma unroll
  for (int t = 0; t < Tn; ++t)
    xT[((size_t)(t*Bn + b) * Vn + v) * Cn + c] = f2bf(vals[t]);
}

// t=0 comb: h0 == 0 so comb = x_0. Writes combc[b][v][c] and combmk[b*C+c][v].
__global__ __launch_bounds__(256) void k_comb0(const unsigned short* __restrict__ xTc,
    unsigned short* __restrict__ combc, unsigned short* __restrict__ combmk){
  __shared__ unsigned short tile[64][65];
  int b = blockIdx.y, v0 = blockIdx.x * 64;
  const unsigned short* xp = xTc + (size_t)b * Vn * Cn;   // plane t=0
  for (int e = threadIdx.x; e < 4096; e += 256){
    int vl = e >> 6, c = e & 63;
    size_t o = (size_t)(v0 + vl) * Cn + c;
    unsigned short s = xp[o];
    combc[(size_t)b*Vn*Cn + o] = s;
    tile[vl][c] = s;
  }
  __syncthreads();
  for (int e = threadIdx.x; e < 4096; e += 256){
    int c = e >> 6, vl = e & 63;
    combmk[((size_t)b*Cn + c)*Vn + v0 + vl] = tile[vl][c];
  }
}

// ---------------------------------------------------------------------------
// Fully fused recurrent step. Block = (w-tile of 64, batch b). 4 waves, 80 KB LDS
// (exactly 2 blocks/CU).
// LDS map: stage buf q @ q*24576 (As 8KB + Bs 16KB, double-buffered);
//          red 32KB @ 49152; xs (x1/x2 bf16 tiles) @ 0 (overlays buf0, after phase1);
//          hs @ 24576, cs @ 32768 (overlay buf1, after phase3).
// Phase 1: dual GEMM over K=1024, BK=64, 2-phase pipelined staging (issue next tile's
//          global_load_lds before computing current; ONE barrier/iter).
// Phase 2: K-half reduce (red) -> x1/x2 bf16 into LDS xs (never global).
// Phase 3: gates GEMM; hop0 B from global combc, hop1/2 from xs.
// Phase 4: pointwise -> hs tile (LDS) -> vectorized coalesced 16B stores of ys2/combc
//          + cs tile transpose -> coalesced combmk stores. (Was: scalar 2B stores at
//          3KB stride = 64 lines/wave-store -> the R3 bottleneck.)
__global__ __launch_bounds__(256) void f_step(
    const unsigned short* __restrict__ combmk_rd,   // [b][c][v] bf16
    const unsigned short* __restrict__ B2T,         // rows 0..1023 A^T, 1024..2047 A2^T
    const unsigned short* __restrict__ Wperm, const float* __restrict__ bperm,
    const unsigned short* __restrict__ combc_rd,    // [b][v][c]
    float* __restrict__ cst, unsigned short* __restrict__ ys2,
    const unsigned short* __restrict__ xTc,
    unsigned short* __restrict__ combc_wr, unsigned short* __restrict__ combmk_wr,
    int t){
  __shared__ char smem[81920];
  int lane = threadIdx.x & 63, wid = threadIdx.x >> 6;
  int mat = wid & 1, kh = wid >> 1;  // wave role in phase 1
  int n0 = blockIdx.x * 64;          // w-tile
  int b  = blockIdx.y;
  const unsigned short* Arow = combmk_rd + (size_t)b * Cn * Vn;

  f32x4 acc[4][4];
  #pragma unroll
  for (int i=0;i<4;i++)
    #pragma unroll
    for (int j=0;j<4;j++) acc[i][j] = fzero();

  // stage 24 x 1KB chunks (8 As + 16 Bs) into buffer at LDS offset sb
  auto stage = [&](int sb, int kc){
    #pragma unroll
    for (int j = 0; j < 6; ++j){
      int idx = wid*6 + j;
      const unsigned short* src;
      int r;
      if (idx < 8){
        r = idx*8 + (lane >> 3);           // As local row (= c)
        src = Arow + (size_t)r * Vn;
      } else {
        int rb = (idx - 8)*8 + (lane >> 3);   // Bs local row 0..127
        int grow = (rb < 64) ? (n0 + rb) : (Vn + n0 + rb - 64);
        r = rb;
        src = B2T + (size_t)grow * Vn;
      }
      int kq = ((lane & 7) ^ (r & 7)) << 3;   // pre-swizzled source granule
      gload_lds16(src + kc + kq, smem + sb + idx*1024);
    }
  };

  // ---- Phase 1: dual GEMM, double-buffered staging ----
  stage(0, 0);
  __syncthreads();
  for (int it = 0; it < 16; ++it){
    if (it < 15) stage(((it+1)&1)*24576, (it+1)*64);   // issue next tile early
    const char* sb = smem + (it&1)*24576;
    int kb = (kh << 5) + ((lane >> 4) << 3);  // k within staged 64
    bh8 a[4], bb[4];
    #pragma unroll
    for (int mf=0; mf<4; ++mf){
      int row = mf*16 + (lane & 15);
      int byte = (row << 7) + (kb << 1);  byte ^= (row & 7) << 4;
      a[mf] = *(const bh8*)(sb + byte);
    }
    #pragma unroll
    for (int nf=0; nf<4; ++nf){
      int rb = mat*64 + nf*16 + (lane & 15);
      int byte = 8192 + (rb << 7) + (kb << 1);  byte ^= (rb & 7) << 4;
      bb[nf] = *(const bh8*)(sb + byte);
    }
    #pragma unroll
    for (int mf=0; mf<4; ++mf)
      #pragma unroll
      for (int nf=0; nf<4; ++nf)
        acc[mf][nf] = __builtin_amdgcn_mfma_f32_16x16x32_bf16(a[mf], bb[nf], acc[mf][nf], 0,0,0);
    __syncthreads();   // drains vmcnt(0): next buffer ready; readers done with cur
  }

  // ---- Phase 2: K-half reduce, then x1/x2 -> LDS xs (bf16, swizzled, @0) ----
  f32x4* red = (f32x4*)(smem + 49152);   // [2][16][64]
  if (kh){
    #pragma unroll
    for (int mf=0; mf<4; ++mf)
      #pragma unroll
      for (int nf=0; nf<4; ++nf) red[((size_t)mat*16 + mf*4+nf)*64 + lane] = acc[mf][nf];
  }
  __syncthreads();
  if (!kh){
    #pragma unroll
    for (int mf=0; mf<4; ++mf)
      #pragma unroll
      for (int nf=0; nf<4; ++nf){
        acc[mf][nf] += red[((size_t)mat*16 + mf*4+nf)*64 + lane];
        int c0 = mf*16 + ((lane >> 4) << 2);
        int w  = nf*16 + (lane & 15);
        int byte = mat*8192 + (w << 7) + (c0 << 1);  byte ^= (w & 7) << 4;
        bh4 p;
        #pragma unroll
        for (int r=0;r<4;r++) p[r] = (short)f2bf(acc[mf][nf][r]);
        *(bh4*)(smem + byte) = p;
      }
  }
  __syncthreads();

  // ---- Phase 3: gates GEMM. Wave = m-tile (64 rows of o' = c*4+gate) ----
  int m0 = wid * 64;
  f32x4 g[4][4];
  #pragma unroll
  for (int i=0;i<4;i++)
    #pragma unroll
    for (int j=0;j<4;j++) g[i][j] = fzero();
  const unsigned short* cb = combc_rd + (size_t)b * Vn * Cn;
  #pragma unroll
  for (int ki = 0; ki < 6; ++ki){
    int hop = ki >> 1, koff = (ki & 1) * 32;
    bh8 a[4], bb[4];
    #pragma unroll
    for (int mf=0; mf<4; ++mf) a[mf] = ld_frag(Wperm, Gn, m0, mf, hop*64 + koff, lane);
    if (hop == 0){
      #pragma unroll
      for (int nf=0; nf<4; ++nf) bb[nf] = ld_frag(cb, Cn, n0, nf, koff, lane);
    } else {
      #pragma unroll
      for (int nf=0; nf<4; ++nf){
        int w = nf*16 + (lane & 15);
        int kk = koff + ((lane >> 4) << 3);
        int byte = (hop-1)*8192 + (w << 7) + (kk << 1);  byte ^= (w & 7) << 4;
        bb[nf] = *(const bh8*)(smem + byte);
      }
    }
    #pragma unroll
    for (int mf=0; mf<4; ++mf)
      #pragma unroll
      for (int nf=0; nf<4; ++nf)
        g[mf][nf] = __builtin_amdgcn_mfma_f32_16x16x32_bf16(a[mf], bb[nf], g[mf][nf], 0,0,0);
  }

  // ---- Phase 4a: LSTM pointwise -> hs tile (LDS @24576, swizzled); cst RMW ----
  char* hs = smem + 24576;
  char* cs = smem + 32768;
  #pragma unroll
  for (int mf = 0; mf < 4; ++mf){
    int oprow = m0 + mf*16 + ((lane>>4)<<2);
    int c = oprow >> 2;
    float4 b4 = *(const float4*)(bperm + oprow);
    #pragma unroll
    for (int nf = 0; nf < 4; ++nf){
      int vl = nf*16 + (lane & 15);
      int v = n0 + vl;
      float gi = sigm(g[mf][nf][0] + b4.x);
      float gf = sigm(g[mf][nf][1] + b4.y);
      float gg =      g[mf][nf][2] + b4.z;     // cell gate used raw (no tanh) per reference
      float go = sigm(g[mf][nf][3] + b4.w);
      size_t ci = ((size_t)b*Cn + c)*Vn + v;
      float cy = gf * cst[ci] + gi * gg;
      cst[ci] = cy;
      unsigned short hb16 = f2bf(go * tanhfast(cy));
      int byte = (vl << 7) + (((c << 1)) ^ ((vl & 7) << 4));
      *(unsigned short*)(hs + byte) = hb16;
    }
  }
  __syncthreads();

  // ---- Phase 4b: coalesced 16B writes of h (ys2), comb (combc), + cs transpose tile ----
  const bool wrc = (t + 1 < Tn);
  unsigned short* ysp = ys2 + (size_t)b * NT * Cn;                 // [v*24 + t][c]
  const unsigned short* xnext = xTc + ((size_t)(t+1)*Bn + b) * (size_t)Vn * Cn;
  unsigned short* ccp = combc_wr  + (size_t)b * Vn * Cn;
  unsigned short* cmp = combmk_wr + (size_t)b * Cn * Vn;
  #pragma unroll
  for (int rnd = 0; rnd < 2; ++rnd){
    int s = rnd*256 + threadIdx.x;     // 512 slots = 64 v x 8 c-granules
    int vl = s >> 3, cg = s & 7;
    int v = n0 + vl;
    bh8 h8 = *(const bh8*)(hs + (vl << 7) + ((cg << 4) ^ ((vl & 7) << 4)));
    *(bh8*)(ysp + ((size_t)v*Tn + t)*Cn + cg*8) = h8;
    if (wrc){
      bh8 x8 = *(const bh8*)(xnext + (size_t)v*Cn + cg*8);
      bh8 c8;
      #pragma unroll
      for (int j = 0; j < 8; ++j)
        c8[j] = (short)f2bf(bf2f((unsigned short)h8[j]) + bf2f((unsigned short)x8[j]));
      *(bh8*)(ccp + (size_t)v*Cn + cg*8) = c8;
      *(bh8*)(cs + (vl << 7) + ((cg << 4) ^ (((vl >> 3) & 7) << 4))) = c8;
    }
  }
  if (wrc){
    __syncthreads();
    // ---- Phase 4c: combmk[c][v] from cs transpose, coalesced 16B stores ----
    #pragma unroll
    for (int rnd = 0; rnd < 2; ++rnd){
      int s = rnd*256 + threadIdx.x;   // 512 slots = 64 c x 8 v-granules
      int c = s >> 3, vg = s & 7;
      bh8 p;
      #pragma unroll
      for (int j = 0; j < 8; ++j){
        int row = vg*8 + j;
        p[j] = (short)*(const unsigned short*)(cs + (row << 7) +
                 (((c << 1)) ^ (((row >> 3) & 7) << 4)));
      }
      *(bh8*)(cmp + (size_t)c*Vn + n0 + vg*8) = p;
    }
  }
}

// Projection as MFMA GEMM per batch: out[b][o][n] = sum_c (Whi+Wlo)[o][c] * ys2[b][n][c] + bo[o]
__global__ __launch_bounds__(256) void k_proj(const unsigned short* __restrict__ ys2,
    const unsigned short* __restrict__ Whi, const unsigned short* __restrict__ Wlo,
    const float* __restrict__ bout, float* __restrict__ out){
  int lane = threadIdx.x & 63, wid = threadIdx.x >> 6;
  int b = blockIdx.y;
  int n0 = blockIdx.x * 256 + wid * 64;
  const unsigned short* yb = ys2 + (size_t)b * NT * Cn;
  f32x4 acc[4][4];
  #pragma unroll
  for (int i=0;i<4;i++)
    #pragma unroll
    for (int j=0;j<4;j++) acc[i][j] = fzero();
  bh8 bfrag[2][4];
  #pragma unroll
  for (int ks=0; ks<2; ++ks)
    #pragma unroll
    for (int nf=0; nf<4; ++nf)
      bfrag[ks][nf] = ld_frag(yb, Cn, n0, nf, ks*32, lane);
  #pragma unroll
  for (int hl=0; hl<2; ++hl){
    const unsigned short* W = hl ? Wlo : Whi;
    #pragma unroll
    for (int ks=0; ks<2; ++ks){
      bh8 a[4];
      #pragma unroll
      for (int mf=0; mf<4; ++mf) a[mf] = ld_frag(W, Cn, 0, mf, ks*32, lane);
      #pragma unroll
      for (int mf=0; mf<4; ++mf)
        #pragma unroll
        for (int nf=0; nf<4; ++nf)
          acc[mf][nf] = __builtin_amdgcn_mfma_f32_16x16x32_bf16(a[mf], bfrag[ks][nf], acc[mf][nf], 0,0,0);
    }
  }
  #pragma unroll
  for (int mf=0; mf<4; ++mf){
    int ob = mf*16 + ((lane>>4)<<2);
    float bo0 = bout[ob+0], bo1 = bout[ob+1], bo2 = bout[ob+2], bo3 = bout[ob+3];
    #pragma unroll
    for (int nf=0; nf<4; ++nf){
      int n = n0 + nf*16 + (lane & 15);
      float* op = out + ((size_t)(b*64 + ob) * NT + n);
      op[0*NT] = acc[mf][nf][0] + bo0;
      op[1*NT] = acc[mf][nf][1] + bo1;
      op[2*NT] = acc[mf][nf][2] + bo2;
      op[3*NT] = acc[mf][nf][3] + bo3;
    }
  }
}

// ---------------------------------------------------------------------------
extern "C" void kernel_launch(void* const* d_in, const int* in_sizes, int n_in,
                              void* d_out, int out_size, void* d_ws, size_t ws_size,
                              hipStream_t stream){
  const float* x   = (const float*)d_in[0];
  const float* A   = (const float*)d_in[1];
  const float* Wg  = (const float*)d_in[2];
  const float* bg  = (const float*)d_in[3];
  const float* Wo  = (const float*)d_in[4];
  const float* bo  = (const float*)d_in[5];
  float* out = (float*)d_out;

  char* ws = (char*)d_ws;
  size_t off = 0;
  auto alloc = [&](size_t bytes)->char*{
    char* p = ws + off; off = (off + bytes + 255) & ~(size_t)255; return p;
  };
  const size_t PLANE = (size_t)Bn*Vn*Cn;   // elements per (b,v,c) plane
  unsigned short* Abf    = (unsigned short*)alloc((size_t)Vn*Vn*2);
  unsigned short* B2T    = (unsigned short*)alloc((size_t)2*Vn*Vn*2);   // [A^T; A2^T]
  float*          A2f    = (float*)         alloc((size_t)Vn*Vn*4);
  unsigned short* Wperm  = (unsigned short*)alloc((size_t)O4*Gn*2);
  float*          bperm  = (float*)         alloc((size_t)O4*4);
  unsigned short* Whi    = (unsigned short*)alloc((size_t)Cn*Cn*2);
  unsigned short* Wlo    = (unsigned short*)alloc((size_t)Cn*Cn*2);
  unsigned short* xTc    = (unsigned short*)alloc((size_t)Tn*PLANE*2);
  unsigned short* ys2    = (unsigned short*)alloc((size_t)Bn*NT*Cn*2);  // [b][v*24+t][c]
  unsigned short* combc  = (unsigned short*)alloc(2*PLANE*2);           // double-buffered
  unsigned short* combmk = (unsigned short*)alloc(2*PLANE*2);           // double-buffered
  float*          cst    = (float*)         alloc(PLANE*4);
  (void)in_sizes; (void)n_in; (void)out_size; (void)ws_size;

  hipMemsetAsync(cst, 0, PLANE*4, stream);

  k_prep_w<<<1, 256, 0, stream>>>(Wg, bg, Wperm, bperm);
  k_prep_wo<<<16, 256, 0, stream>>>(Wo, Whi, Wlo);
  k_transq<<<dim3(16,16), 256, 0, stream>>>(A, Abf, B2T);                 // rows 0..1023 = A^T
  k_gemm_a2<<<dim3(16,16), 256, 0, stream>>>(Abf, B2T, A2f);
  k_transq<<<dim3(16,16), 256, 0, stream>>>(A2f, (unsigned short*)nullptr,
                                            B2T + (size_t)Vn*Vn);         // rows 1024.. = A2^T
  k_transpose_x<<<dim3(256,32), 256, 0, stream>>>(x, xTc);

  // t=0: h0 == 0 so comb = x_0 (fills buffer 0 of both comb layouts)
  k_comb0<<<dim3(16,Bn), 256, 0, stream>>>(xTc, combc, combmk);

  for (int t = 0; t < Tn; ++t){
    f_step<<<dim3(16,Bn), 256, 0, stream>>>(
        combmk + (size_t)(t & 1) * PLANE, B2T, Wperm, bperm,
        combc  + (size_t)(t & 1) * PLANE, cst, ys2, xTc,
        combc  + (size_t)((t + 1) & 1) * PLANE,
        combmk + (size_t)((t + 1) & 1) * PLANE, t);
  }
  k_proj<<<dim3(96,32), 256, 0, stream>>>(ys2, Whi, Wlo, bo, out);
}